// Round 1
// baseline (485.890 us; speedup 1.0000x reference)
//
#include <hip/hip_runtime.h>

// NegativeKLDiv: bs=2048, n1=n2=4, d=4608, fp32.
// out[b,i,j] = cross[b,i,j] - ent[b,i]
//   ent[b,i]   = sum_d p*log(p+eps),  p = input1*mask1
//   cross[b,i,j] = sum_d p_i * log(q_j+eps), q = input2*mask2
// Memory-bound: 604 MB read once -> ~96us floor at 6.3 TB/s.

constexpr int   D   = 4608;
constexpr int   DV  = D / 4;    // 1152 float4 per row
constexpr int   NT  = 256;      // threads per block (4 waves)
constexpr float EPS = 1e-9f;

__global__ __launch_bounds__(NT)
void nkld_kernel(const float* __restrict__ in1, const float* __restrict__ m1,
                 const float* __restrict__ in2, const float* __restrict__ m2,
                 float* __restrict__ out)
{
    const int b   = blockIdx.x;     // one block per batch
    const int tid = threadIdx.x;

    const size_t base = (size_t)b * 4 * D;
    const float4* p1 = reinterpret_cast<const float4*>(in1 + base);
    const float4* g1 = reinterpret_cast<const float4*>(m1  + base);
    const float4* p2 = reinterpret_cast<const float4*>(in2 + base);
    const float4* g2 = reinterpret_cast<const float4*>(m2  + base);

    float ent[4]      = {0.f, 0.f, 0.f, 0.f};
    float cross[4][4] = {{0.f,0.f,0.f,0.f},{0.f,0.f,0.f,0.f},
                         {0.f,0.f,0.f,0.f},{0.f,0.f,0.f,0.f}};

    for (int v = tid; v < DV; v += NT) {
        float4 pv[4];
        float4 lq[4];
        #pragma unroll
        for (int i = 0; i < 4; ++i) {
            float4 a  = p1[(size_t)i * DV + v];
            float4 ma = g1[(size_t)i * DV + v];
            float4 p  = make_float4(a.x * ma.x, a.y * ma.y, a.z * ma.z, a.w * ma.w);
            pv[i] = p;
            ent[i] += p.x * __logf(p.x + EPS);
            ent[i] += p.y * __logf(p.y + EPS);
            ent[i] += p.z * __logf(p.z + EPS);
            ent[i] += p.w * __logf(p.w + EPS);
        }
        #pragma unroll
        for (int j = 0; j < 4; ++j) {
            float4 c  = p2[(size_t)j * DV + v];
            float4 mc = g2[(size_t)j * DV + v];
            lq[j] = make_float4(__logf(c.x * mc.x + EPS),
                                __logf(c.y * mc.y + EPS),
                                __logf(c.z * mc.z + EPS),
                                __logf(c.w * mc.w + EPS));
        }
        #pragma unroll
        for (int i = 0; i < 4; ++i) {
            #pragma unroll
            for (int j = 0; j < 4; ++j) {
                cross[i][j] += pv[i].x * lq[j].x + pv[i].y * lq[j].y
                             + pv[i].z * lq[j].z + pv[i].w * lq[j].w;
            }
        }
    }

    // 20 partial sums -> block reduction
    float vals[20];
    #pragma unroll
    for (int i = 0; i < 4; ++i) vals[i] = ent[i];
    #pragma unroll
    for (int i = 0; i < 4; ++i)
        #pragma unroll
        for (int j = 0; j < 4; ++j) vals[4 + i * 4 + j] = cross[i][j];

    // wave64 butterfly (shfl_down tree; lane 0 holds wave total)
    #pragma unroll
    for (int off = 32; off > 0; off >>= 1) {
        #pragma unroll
        for (int k = 0; k < 20; ++k)
            vals[k] += __shfl_down(vals[k], off, 64);
    }

    __shared__ float red[4][20];
    const int wave = tid >> 6;
    const int lane = tid & 63;
    if (lane == 0) {
        #pragma unroll
        for (int k = 0; k < 20; ++k) red[wave][k] = vals[k];
    }
    __syncthreads();

    if (tid < 16) {
        const int i = tid >> 2;   // n1 index
        float c = 0.f, e = 0.f;
        #pragma unroll
        for (int w = 0; w < 4; ++w) {
            c += red[w][4 + tid];
            e += red[w][i];
        }
        // reference returns -(ent - cross) = cross - ent
        out[(size_t)b * 16 + tid] = c - e;
    }
}

extern "C" void kernel_launch(void* const* d_in, const int* in_sizes, int n_in,
                              void* d_out, int out_size, void* d_ws, size_t ws_size,
                              hipStream_t stream) {
    const float* in1 = (const float*)d_in[0];
    const float* m1  = (const float*)d_in[1];
    const float* in2 = (const float*)d_in[2];
    const float* m2  = (const float*)d_in[3];
    float* out = (float*)d_out;
    nkld_kernel<<<dim3(2048), dim3(NT), 0, stream>>>(in1, m1, in2, m2, out);
}